// Round 5
// baseline (908.434 us; speedup 1.0000x reference)
//
#include <hip/hip_runtime.h>
#include <hip/hip_bf16.h>
#include <math.h>

#define NJ 30000
#define NS 12000
#define E_JS 300000
#define E_SJ 300000
#define E_SS 150000
#define ETOT (E_JS + E_SJ + E_SS + NS)   // 762000 incl. ss self loops
#define NBINS (NS + NJ + NS)             // 54000 combined dst bins
#define NBUK ((NBINS + 63) / 64)         // 844 coarse buckets (64 bins each)
#define SBERT 384
#define HIDDEN 128
#define OUTD 128

static inline int cdiv(int a, int b) { return (a + b - 1) / b; }

typedef __attribute__((ext_vector_type(8))) short bf8_t;
typedef __attribute__((ext_vector_type(4))) float f4_t;
typedef unsigned short u16;

__device__ inline float bf2f(unsigned short u) {
    union { unsigned int i; float f; } z; z.i = ((unsigned int)u) << 16; return z.f;
}
__device__ inline unsigned short f2bf(float f) {
    unsigned int x = __float_as_uint(f);
    unsigned int r = (x + 0x7fffu + ((x >> 16) & 1u)) >> 16;   // RNE
    return (unsigned short)r;
}

// ---------------------------------------------------------------------------
// cast fp32 x_job/x_skill -> bf16
// ---------------------------------------------------------------------------
__global__ void k_cast_x(const float* __restrict__ xj, const float* __restrict__ xs,
                         unsigned short* __restrict__ oj, unsigned short* __restrict__ os) {
    const int NJE = NJ * SBERT;
    const int TOT = (NJ + NS) * SBERT;
    int i4 = (blockIdx.x * 256 + threadIdx.x) * 4;
    if (i4 >= TOT) return;
    const float* src; unsigned short* dst; int off;
    if (i4 < NJE) { src = xj; dst = oj; off = i4; }
    else { src = xs; dst = os; off = i4 - NJE; }
    float4 v = *(const float4*)&src[off];
    ushort4 o; o.x = f2bf(v.x); o.y = f2bf(v.y); o.z = f2bf(v.z); o.w = f2bf(v.w);
    *(ushort4*)&dst[off] = o;
}

// ---------------------------------------------------------------------------
// batched weight transpose+cast: dst[n*K+k] = (bf16)src[k*N+n]
// ---------------------------------------------------------------------------
struct CastT { const float* src; unsigned short* dst; int K; int N; };
struct CastTList { CastT m[13]; };

__global__ void k_castT(CastTList L) {
    CastT c = L.m[blockIdx.y];
    int idx = blockIdx.x * 256 + threadIdx.x;
    int total = c.K * c.N;
    if (idx >= total) return;
    int n = idx / c.K, k = idx % c.K;
    c.dst[idx] = f2bf(c.src[(size_t)k * c.N + n]);
}

// ---------------------------------------------------------------------------
// Precompute ws_a / wd_a (+ zero the bucket counters for the CSR build)
// ---------------------------------------------------------------------------
__global__ void k_wa(const float* __restrict__ Ws, const float* __restrict__ as,
                     const float* __restrict__ Wd, const float* __restrict__ ad,
                     float* __restrict__ wsa, float* __restrict__ wda,
                     int* __restrict__ bcnt) {
    int id = blockIdx.x * 256 + threadIdx.x;   // 2 * 1536 total
    if (id < NBUK) bcnt[id] = 0;
    if (id >= 2 * 1536) return;
    int which = id / 1536;
    int r = id % 1536;
    int lr = r / 256;       // 0..5  (l*3 + rel)
    int kh = r % 256;
    int k = kh / 2, h = kh % 2;
    const float* W = which ? Wd : Ws;
    const float* a = which ? ad : as;
    const float* wrow = W + ((size_t)(lr * 128 + k)) * 256 + h * 128;
    const float* arow = a + (size_t)(lr * 2 + h) * 128;
    float acc = 0.f;
    for (int c = 0; c < 128; ++c) acc += wrow[c] * arow[c];
    (which ? wda : wsa)[lr * 256 + k * 2 + h] = acc;
}

// ---------------------------------------------------------------------------
// Batched bf16 MFMA GEMM: up to 2 jobs per dispatch.
//   Y[M,ldY](n0..n0+127) = X[M,K] @ Wt[n][k]^T ; BM=64, 4 waves x (16m x 128n).
//   EPI: 0 none->bf16, 1 +bias->fp32, 2 +bias,relu->bf16, 3 +bias,LN,relu->bf16
// ---------------------------------------------------------------------------
struct GJob {
    const unsigned short* X; const unsigned short* Wt;
    const float* bias; const float* gamma; const float* beta;
    void* Y; int M; int K; int N; int ldY;
};
struct GPair { GJob a; GJob b; int blocksA; };

template <int EPI>
__global__ __launch_bounds__(256) void k_mgemm(GPair P) {
    int mb = blockIdx.x;
    GJob g = (mb < P.blocksA) ? P.a : P.b;
    if (mb >= P.blocksA) mb -= P.blocksA;
    const int n0 = blockIdx.y * 128;
    if (n0 >= g.N) return;
    const int row0 = mb * 64;

    __shared__ __align__(16) unsigned short Al[64][40];
    __shared__ __align__(16) unsigned short Bl[128][40];
    const int t = threadIdx.x;
    const int wave = t >> 6, lane = t & 63;
    const int q = lane >> 4, c = lane & 15;
    const int K = g.K;

    f4_t acc[8];
#pragma unroll
    for (int nt = 0; nt < 8; ++nt) acc[nt] = (f4_t){0.f, 0.f, 0.f, 0.f};

    for (int k0 = 0; k0 < K; k0 += 32) {
#pragma unroll
        for (int it = 0; it < 3; ++it) {
            int idx = t + it * 256;          // 768 chunks: 64 A rows + 128 B rows, 4x16B
            int r = idx >> 2, cc = (idx & 3) * 8;
            if (r < 64) {
                int gr = row0 + r;
                uint4 va = (gr < g.M) ? *(const uint4*)&g.X[(size_t)gr * K + k0 + cc]
                                      : make_uint4(0u, 0u, 0u, 0u);
                *(uint4*)&Al[r][cc] = va;
            } else {
                int br = r - 64;
                *(uint4*)&Bl[br][cc] = *(const uint4*)&g.Wt[(size_t)(n0 + br) * K + k0 + cc];
            }
        }
        __syncthreads();
        bf8_t af = *(const bf8_t*)&Al[wave * 16 + c][q * 8];
#pragma unroll
        for (int nt = 0; nt < 8; ++nt) {
            bf8_t bfr = *(const bf8_t*)&Bl[nt * 16 + c][q * 8];
            acc[nt] = __builtin_amdgcn_mfma_f32_16x16x32_bf16(af, bfr, acc[nt], 0, 0, 0);
        }
        __syncthreads();
    }

    float bcol[8], gcol[8], becol[8];
#pragma unroll
    for (int nt = 0; nt < 8; ++nt) {
        bcol[nt] = (EPI >= 1) ? g.bias[n0 + nt * 16 + c] : 0.f;
        if constexpr (EPI == 3) {
            gcol[nt] = g.gamma[nt * 16 + c];
            becol[nt] = g.beta[nt * 16 + c];
        }
    }

#pragma unroll
    for (int r = 0; r < 4; ++r) {
        int grow = row0 + wave * 16 + q * 4 + r;
        float v[8];
#pragma unroll
        for (int nt = 0; nt < 8; ++nt) v[nt] = acc[nt][r] + bcol[nt];
        if constexpr (EPI == 3) {
            float s = 0.f, ss = 0.f;
#pragma unroll
            for (int nt = 0; nt < 8; ++nt) { s += v[nt]; ss += v[nt] * v[nt]; }
#pragma unroll
            for (int m = 8; m >= 1; m >>= 1) {
                s += __shfl_xor(s, m, 64);
                ss += __shfl_xor(ss, m, 64);
            }
            float mu = s * (1.f / 128.f);
            float var = ss * (1.f / 128.f) - mu * mu;
            float rs = rsqrtf(var + 1e-5f);
#pragma unroll
            for (int nt = 0; nt < 8; ++nt)
                v[nt] = fmaxf((v[nt] - mu) * rs * gcol[nt] + becol[nt], 0.f);
        } else if constexpr (EPI == 2) {
#pragma unroll
            for (int nt = 0; nt < 8; ++nt) v[nt] = fmaxf(v[nt], 0.f);
        }
        if (grow < g.M) {
            if constexpr (EPI == 1) {
                float* Y = (float*)g.Y;
#pragma unroll
                for (int nt = 0; nt < 8; ++nt)
                    Y[(size_t)grow * g.ldY + n0 + nt * 16 + c] = v[nt];
            } else {
                unsigned short* Y = (unsigned short*)g.Y;
#pragma unroll
                for (int nt = 0; nt < 8; ++nt)
                    Y[(size_t)grow * g.ldY + n0 + nt * 16 + c] = f2bf(v[nt]);
            }
        }
    }
}

// ---------------------------------------------------------------------------
// Per-layer alpha precompute (unchanged)
// ---------------------------------------------------------------------------
__global__ __launch_bounds__(256) void k_alpha_all(
    const unsigned short* __restrict__ xj, const unsigned short* __restrict__ xs,
    const float* __restrict__ wsa, const float* __restrict__ wda, int l3,
    float* __restrict__ aJ, float* __restrict__ aS) {
    int wave = threadIdx.x >> 6, lane = threadIdx.x & 63;
    int node = blockIdx.x * 4 + wave;
    if (node < NJ) {
        ushort2 xv = *(const ushort2*)&xj[(size_t)node * 128 + lane * 2];
        float x0 = bf2f(xv.x), x1 = bf2f(xv.y);
        float4 w0 = *(const float4*)&wsa[(size_t)(l3 + 0) * 256 + lane * 4];
        float4 w1 = *(const float4*)&wda[(size_t)(l3 + 1) * 256 + lane * 4];
        float p0 = x0 * w0.x + x1 * w0.z, p1 = x0 * w0.y + x1 * w0.w;
        float p2 = x0 * w1.x + x1 * w1.z, p3 = x0 * w1.y + x1 * w1.w;
#pragma unroll
        for (int m = 32; m >= 1; m >>= 1) {
            p0 += __shfl_xor(p0, m, 64); p1 += __shfl_xor(p1, m, 64);
            p2 += __shfl_xor(p2, m, 64); p3 += __shfl_xor(p3, m, 64);
        }
        if (lane == 0) {
            float4* o = (float4*)&aJ[(size_t)node * 4];
            *o = make_float4(p0, p1, p2, p3);
        }
    } else if (node < NJ + NS) {
        int n = node - NJ;
        ushort2 xv = *(const ushort2*)&xs[(size_t)n * 128 + lane * 2];
        float x0 = bf2f(xv.x), x1 = bf2f(xv.y);
        float4 wA = *(const float4*)&wsa[(size_t)(l3 + 2) * 256 + lane * 4];  // as ss
        float4 wB = *(const float4*)&wda[(size_t)(l3 + 0) * 256 + lane * 4];  // ad js
        float4 wC = *(const float4*)&wsa[(size_t)(l3 + 1) * 256 + lane * 4];  // as sj
        float4 wD = *(const float4*)&wda[(size_t)(l3 + 2) * 256 + lane * 4];  // ad ss
        float p0 = x0 * wA.x + x1 * wA.z, p1 = x0 * wA.y + x1 * wA.w;
        float p2 = x0 * wB.x + x1 * wB.z, p3 = x0 * wB.y + x1 * wB.w;
        float p4 = x0 * wC.x + x1 * wC.z, p5 = x0 * wC.y + x1 * wC.w;
        float p6 = x0 * wD.x + x1 * wD.z, p7 = x0 * wD.y + x1 * wD.w;
#pragma unroll
        for (int m = 32; m >= 1; m >>= 1) {
            p0 += __shfl_xor(p0, m, 64); p1 += __shfl_xor(p1, m, 64);
            p2 += __shfl_xor(p2, m, 64); p3 += __shfl_xor(p3, m, 64);
            p4 += __shfl_xor(p4, m, 64); p5 += __shfl_xor(p5, m, 64);
            p6 += __shfl_xor(p6, m, 64); p7 += __shfl_xor(p7, m, 64);
        }
        if (lane == 0) {
            float4* o = (float4*)&aS[(size_t)n * 8];
            o[0] = make_float4(p0, p1, p2, p3);
            o[1] = make_float4(p4, p5, p6, p7);
        }
    }
}

// ---------------------------------------------------------------------------
// Two-level bucketed CSR build.
// bin layout: [0,NS) js | [NS,NS+NJ) sj | [NS+NJ,NBINS) ss (incl self loops)
// bucket = bin >> 6 (NBUK buckets of 64 bins)
// ---------------------------------------------------------------------------
__device__ inline void edge_decode(int e, const int* js_src, const int* js_dst,
                                   const int* sj_src, const int* sj_dst,
                                   const int* ss_src, const int* ss_dst,
                                   int& src, int& bin) {
    if (e < E_JS) { src = js_src[e]; bin = js_dst[e]; }
    else if (e < E_JS + E_SJ) { int i = e - E_JS; src = sj_src[i]; bin = NS + sj_dst[i]; }
    else if (e < E_JS + E_SJ + E_SS) { int i = e - E_JS - E_SJ; src = ss_src[i]; bin = NS + NJ + ss_dst[i]; }
    else { int i = e - E_JS - E_SJ - E_SS; src = i; bin = NS + NJ + i; }
}

__global__ void k_bucket_hist(const int* __restrict__ js_src, const int* __restrict__ js_dst,
                              const int* __restrict__ sj_src, const int* __restrict__ sj_dst,
                              const int* __restrict__ ss_src, const int* __restrict__ ss_dst,
                              int* __restrict__ bcnt) {
    int e = blockIdx.x * 256 + threadIdx.x;
    if (e >= ETOT) return;
    int src, bin;
    edge_decode(e, js_src, js_dst, sj_src, sj_dst, ss_src, ss_dst, src, bin);
    atomicAdd(&bcnt[bin >> 6], 1);
}

__global__ void k_bucket_scan(const int* __restrict__ bcnt, int* __restrict__ bukoff,
                              int* __restrict__ bukcur) {
    __shared__ int sd[1024];
    int t = threadIdx.x;
    int v = (t < NBUK) ? bcnt[t] : 0;
    sd[t] = v;
    __syncthreads();
    for (int off = 1; off < 1024; off <<= 1) {
        int tmp = (t >= off) ? sd[t - off] : 0;
        __syncthreads();
        sd[t] += tmp;
        __syncthreads();
    }
    if (t < NBUK) { int ex = sd[t] - v; bukoff[t] = ex; bukcur[t] = ex; }
    if (t == 0) bukoff[NBUK] = ETOT;
}

__global__ void k_scatter_pairs(const int* __restrict__ js_src, const int* __restrict__ js_dst,
                                const int* __restrict__ sj_src, const int* __restrict__ sj_dst,
                                const int* __restrict__ ss_src, const int* __restrict__ ss_dst,
                                int* __restrict__ bukcur, uint2* __restrict__ pairs) {
    int e = blockIdx.x * 256 + threadIdx.x;
    if (e >= ETOT) return;
    int src, bin;
    edge_decode(e, js_src, js_dst, sj_src, sj_dst, ss_src, ss_dst, src, bin);
    int pos = atomicAdd(&bukcur[bin >> 6], 1);
    pairs[pos] = make_uint2((unsigned)src, (unsigned)bin);
}

// one block per bucket: local 64-bin CSR in LDS, dense contiguous esrc writes
__global__ __launch_bounds__(256) void k_finalize(
    const uint2* __restrict__ pairs, const int* __restrict__ bukoff,
    int* __restrict__ offs, int* __restrict__ esrc) {
    int b = blockIdx.x, t = threadIdx.x;
    int base = bukoff[b], endi = bukoff[b + 1];
    __shared__ int cnt[64], excl[64], curs[64];
    if (t < 64) cnt[t] = 0;
    __syncthreads();
    for (int i = base + t; i < endi; i += 256)
        atomicAdd(&cnt[pairs[i].y & 63], 1);
    __syncthreads();
    if (t < 64) {
        int v = cnt[t];
        int inc = v;
#pragma unroll
        for (int off = 1; off < 64; off <<= 1) {
            int tmp = __shfl_up(inc, off, 64);
            if (t >= off) inc += tmp;
        }
        excl[t] = inc - v;
        curs[t] = inc - v;
    }
    __syncthreads();
    for (int i = base + t; i < endi; i += 256) {
        uint2 p = pairs[i];
        int lb = p.y & 63;
        int pos = atomicAdd(&curs[lb], 1);
        esrc[base + pos] = (int)p.x;
    }
    if (t < 64) {
        int bin = b * 64 + t;
        if (bin < NBINS) offs[bin] = base + excl[t];
    }
    if (b == 0 && t == 0) offs[NBINS] = ETOT;
}

// ---------------------------------------------------------------------------
// Fused gather + edge softmax, 4-way unrolled edge loop (clamped tail).
// ---------------------------------------------------------------------------
__global__ __launch_bounds__(256) void k_gather(
    const int* __restrict__ offs, const int* __restrict__ esrc,
    const float* __restrict__ aS, int sStride,
    const float* __restrict__ aD, int dStride,
    const unsigned short* __restrict__ hs, int hsLd,
    const float* __restrict__ bias,
    unsigned short* __restrict__ out, int Nd, int accumulate) {
    int wave = threadIdx.x >> 6, lane = threadIdx.x & 63;
    int d = blockIdx.x * 4 + wave;
    if (d >= Nd) return;
    int c = lane * 4;
    int h = (c >= 128) ? 1 : 0;
    float ad = aD[(size_t)d * dStride + h];
    int beg = offs[d], end = offs[d + 1];
    float ax = 0.f, ay = 0.f, az = 0.f, aw = 0.f, den = 0.f;
    for (int j = beg; j < end; j += 4) {
        int j1 = j + 1 < end ? j + 1 : end - 1;
        int j2 = j + 2 < end ? j + 2 : end - 1;
        int j3 = j + 3 < end ? j + 3 : end - 1;
        int s0 = esrc[j], s1 = esrc[j1], s2 = esrc[j2], s3 = esrc[j3];
        float as0 = aS[(size_t)s0 * sStride + h];
        float as1 = aS[(size_t)s1 * sStride + h];
        float as2 = aS[(size_t)s2 * sStride + h];
        float as3 = aS[(size_t)s3 * sStride + h];
        ushort4 v0 = *(const ushort4*)&hs[(size_t)s0 * hsLd + c];
        ushort4 v1 = *(const ushort4*)&hs[(size_t)s1 * hsLd + c];
        ushort4 v2 = *(const ushort4*)&hs[(size_t)s2 * hsLd + c];
        ushort4 v3 = *(const ushort4*)&hs[(size_t)s3 * hsLd + c];
        float e0 = as0 + ad; e0 = e0 > 0.f ? e0 : 0.2f * e0;
        float e1 = as1 + ad; e1 = e1 > 0.f ? e1 : 0.2f * e1;
        float e2 = as2 + ad; e2 = e2 > 0.f ? e2 : 0.2f * e2;
        float e3 = as3 + ad; e3 = e3 > 0.f ? e3 : 0.2f * e3;
        float p0 = __expf(e0);
        float p1 = (j + 1 < end) ? __expf(e1) : 0.f;
        float p2 = (j + 2 < end) ? __expf(e2) : 0.f;
        float p3 = (j + 3 < end) ? __expf(e3) : 0.f;
        ax += p0 * bf2f(v0.x) + p1 * bf2f(v1.x) + p2 * bf2f(v2.x) + p3 * bf2f(v3.x);
        ay += p0 * bf2f(v0.y) + p1 * bf2f(v1.y) + p2 * bf2f(v2.y) + p3 * bf2f(v3.y);
        az += p0 * bf2f(v0.z) + p1 * bf2f(v1.z) + p2 * bf2f(v2.z) + p3 * bf2f(v3.z);
        aw += p0 * bf2f(v0.w) + p1 * bf2f(v1.w) + p2 * bf2f(v2.w) + p3 * bf2f(v3.w);
        den += p0 + p1 + p2 + p3;
    }
    float sc = 1.f / (den + 1e-16f);
    float4 b4 = *(const float4*)&bias[c];
    unsigned short* op = &out[(size_t)d * 256 + c];
    float o0 = ax * sc + b4.x, o1 = ay * sc + b4.y;
    float o2 = az * sc + b4.z, o3 = aw * sc + b4.w;
    if (accumulate) {
        ushort4 prev = *(ushort4*)op;
        o0 += bf2f(prev.x); o1 += bf2f(prev.y); o2 += bf2f(prev.z); o3 += bf2f(prev.w);
    }
    ushort4 o; o.x = f2bf(o0); o.y = f2bf(o1); o.z = f2bf(o2); o.w = f2bf(o3);
    *(ushort4*)op = o;
}

// ---------------------------------------------------------------------------
// q = query @ Wq + bq  (fp32)
// ---------------------------------------------------------------------------
__global__ void k_qvec(const float* __restrict__ query, const float* __restrict__ Wq,
                       const float* __restrict__ bq, float* __restrict__ qv) {
    int c = threadIdx.x;  // 128
    float acc = bq[c];
    for (int k = 0; k < SBERT; ++k) acc += query[k] * Wq[(size_t)k * 128 + c];
    qv[c] = acc;
}

// scores[r] = job_emb[r] . q   (wave per row, job_emb fp32)
__global__ __launch_bounds__(256) void k_scores(const float* __restrict__ jemb,
                                                const float* __restrict__ q,
                                                float* __restrict__ sc, int n) {
    int wave = threadIdx.x >> 6, lane = threadIdx.x & 63;
    int r = blockIdx.x * 4 + wave;
    if (r >= n) return;
    float2 a = *(const float2*)&jemb[(size_t)r * 128 + lane * 2];
    float2 b = *(const float2*)&q[lane * 2];
    float p = a.x * b.x + a.y * b.y;
#pragma unroll
    for (int m = 32; m >= 1; m >>= 1) p += __shfl_xor(p, m, 64);
    if (lane == 0) sc[r] = p;
}

// ---------------------------------------------------------------------------
extern "C" void kernel_launch(void* const* d_in, const int* in_sizes, int n_in,
                              void* d_out, int out_size, void* d_ws, size_t ws_size,
                              hipStream_t stream) {
    const float* x_job   = (const float*)d_in[0];
    const float* x_skill = (const float*)d_in[1];
    const int* js_src = (const int*)d_in[2];
    const int* js_dst = (const int*)d_in[3];
    const int* sj_src = (const int*)d_in[4];
    const int* sj_dst = (const int*)d_in[5];
    const int* ss_src = (const int*)d_in[6];
    const int* ss_dst = (const int*)d_in[7];
    const float* query    = (const float*)d_in[8];
    const float* W0_job   = (const float*)d_in[9];
    const float* b0_job   = (const float*)d_in[10];
    const float* g0_job   = (const float*)d_in[11];
    const float* be0_job  = (const float*)d_in[12];
    const float* W0_skill = (const float*)d_in[13];
    const float* b0_skill = (const float*)d_in[14];
    const float* g0_skill = (const float*)d_in[15];
    const float* be0_skill= (const float*)d_in[16];
    const float* gat_Ws = (const float*)d_in[17];
    const float* gat_Wd = (const float*)d_in[18];
    const float* gat_as = (const float*)d_in[19];
    const float* gat_ad = (const float*)d_in[20];
    const float* gat_b  = (const float*)d_in[21];
    const float* inter_W = (const float*)d_in[22];
    const float* inter_b = (const float*)d_in[23];
    const float* Wjf = (const float*)d_in[24];
    const float* bjf = (const float*)d_in[25];
    const float* Wq  = (const float*)d_in[26];
    const float* bq  = (const float*)d_in[27];

    // workspace carve (256B aligned bump allocator)
    char* w = (char*)d_ws;
    auto alloc = [&](size_t bytes) -> void* {
        void* p = (void*)w;
        w += (bytes + 255) & ~(size_t)255;
        return p;
    };
    u16* xjob_b   = (u16*)alloc((size_t)NJ * SBERT * 2);
    u16* xskill_b = (u16*)alloc((size_t)NS * SBERT * 2);
    u16* xj  = (u16*)alloc((size_t)NJ * 128 * 2);
    u16* xs  = (u16*)alloc((size_t)NS * 128 * 2);
    u16* hs1 = (u16*)alloc((size_t)NJ * 256 * 2);   // job-side projection (js)
    u16* hs2 = (u16*)alloc((size_t)NS * 512 * 2);   // skill-side: [sj | ss]
    u16* oj  = (u16*)alloc((size_t)NJ * 256 * 2);
    u16* os  = (u16*)alloc((size_t)NS * 256 * 2);
    // transposed bf16 weights
    u16* WtW0j = (u16*)alloc((size_t)SBERT * 128 * 2);
    u16* WtW0s = (u16*)alloc((size_t)SBERT * 128 * 2);
    u16* WtWs  = (u16*)alloc((size_t)6 * 128 * 256 * 2);   // [lr][256][128]
    u16* WtI   = (u16*)alloc((size_t)4 * 256 * 128 * 2);   // [i][128][256]
    u16* WtJf  = (u16*)alloc((size_t)128 * 128 * 2);
    float* aJ = (float*)alloc((size_t)NJ * 4 * 4);
    float* aS = (float*)alloc((size_t)NS * 8 * 4);
    float* wsa = (float*)alloc(6 * 256 * 4);
    float* wda = (float*)alloc(6 * 256 * 4);
    int* bcnt   = (int*)alloc((size_t)NBUK * 4);
    int* bukoff = (int*)alloc((size_t)(NBUK + 1) * 4);
    int* bukcur = (int*)alloc((size_t)NBUK * 4);
    uint2* pairs = (uint2*)alloc((size_t)ETOT * 8);
    int* offs = (int*)alloc((size_t)(NBINS + 1) * 4);
    int* esrc = (int*)alloc((size_t)ETOT * 4);

    float* out = (float*)d_out;
    float* scores  = out;
    float* job_emb = out + NJ;
    float* qv      = out + NJ + (size_t)NJ * 128;

    const int mbJ = cdiv(NJ, 64);   // 469
    const int mbS = cdiv(NS, 64);   // 188

    // --- casts: x -> bf16, weights -> transposed bf16 ---
    {
        int tot4 = (NJ + NS) * SBERT / 4;
        k_cast_x<<<cdiv(tot4, 256), 256, 0, stream>>>(x_job, x_skill, xjob_b, xskill_b);
        CastTList L;
        L.m[0] = {W0_job, WtW0j, SBERT, 128};
        L.m[1] = {W0_skill, WtW0s, SBERT, 128};
        for (int lr = 0; lr < 6; ++lr)
            L.m[2 + lr] = {gat_Ws + (size_t)lr * 128 * 256, WtWs + (size_t)lr * 256 * 128, 128, 256};
        for (int i = 0; i < 4; ++i)
            L.m[8 + i] = {inter_W + (size_t)i * 256 * 128, WtI + (size_t)i * 128 * 256, 256, 128};
        L.m[12] = {Wjf, WtJf, 128, 128};
        k_castT<<<dim3(cdiv(SBERT * 128, 256), 13), 256, 0, stream>>>(L);
    }

    // --- precompute attention weight vectors (+ zero bucket counters) ---
    k_wa<<<cdiv(2 * 1536, 256), 256, 0, stream>>>(gat_Ws, gat_as, gat_Wd, gat_ad, wsa, wda, bcnt);

    // --- bucketed CSR build (layer-invariant) ---
    k_bucket_hist<<<cdiv(ETOT, 256), 256, 0, stream>>>(js_src, js_dst, sj_src, sj_dst,
                                                       ss_src, ss_dst, bcnt);
    k_bucket_scan<<<1, 1024, 0, stream>>>(bcnt, bukoff, bukcur);
    k_scatter_pairs<<<cdiv(ETOT, 256), 256, 0, stream>>>(js_src, js_dst, sj_src, sj_dst,
                                                         ss_src, ss_dst, bukcur, pairs);
    k_finalize<<<NBUK, 256, 0, stream>>>(pairs, bukoff, offs, esrc);

    // --- initial linear + LN + relu (batched job+skill) ---
    {
        GPair P;
        P.a = {xjob_b, WtW0j, b0_job, g0_job, be0_job, xj, NJ, SBERT, 128, 128};
        P.b = {xskill_b, WtW0s, b0_skill, g0_skill, be0_skill, xs, NS, SBERT, 128, 128};
        P.blocksA = mbJ;
        k_mgemm<3><<<dim3(mbJ + mbS, 1), 256, 0, stream>>>(P);
    }

    for (int l = 0; l < 2; ++l) {
        int l3 = l * 3;
        k_alpha_all<<<cdiv(NJ + NS, 4), 256, 0, stream>>>(xj, xs, wsa, wda, l3, aJ, aS);

        // projections: hs1 = xj @ Ws[js] (N=256); hs2 = xs @ [Ws[sj]|Ws[ss]] (N=512)
        {
            GPair P;
            P.a = {xj, WtWs + (size_t)(l3 + 0) * 256 * 128, nullptr, nullptr, nullptr,
                   hs1, NJ, 128, 256, 256};
            P.b = {xs, WtWs + (size_t)(l3 + 1) * 256 * 128, nullptr, nullptr, nullptr,
                   hs2, NS, 128, 512, 512};
            P.blocksA = mbJ;
            k_mgemm<0><<<dim3(mbJ + mbS, 4), 256, 0, stream>>>(P);
        }

        // o_s = GAT_js(xj->xs) + GAT_ss(xs->xs)
        k_gather<<<cdiv(NS, 4), 256, 0, stream>>>(
            offs, esrc, aJ + 0, 4, aS + 2, 8, hs1, 256,
            gat_b + (size_t)(l3 + 0) * 256, os, NS, 0);
        k_gather<<<cdiv(NS, 4), 256, 0, stream>>>(
            offs + NS + NJ, esrc, aS + 0, 8, aS + 6, 8, hs2 + 256, 512,
            gat_b + (size_t)(l3 + 2) * 256, os, NS, 1);
        // o_j = GAT_sj(xs->xj)
        k_gather<<<cdiv(NJ, 4), 256, 0, stream>>>(
            offs + NS, esrc, aS + 4, 8, aJ + 2, 4, hs2, 512,
            gat_b + (size_t)(l3 + 1) * 256, oj, NJ, 0);

        // inter linears + relu (batched job+skill, overwrite xj, xs)
        {
            GPair P;
            P.a = {oj, WtI + (size_t)(l * 2 + 0) * 128 * 256, inter_b + (size_t)(l * 2 + 0) * 128,
                   nullptr, nullptr, xj, NJ, 256, 128, 128};
            P.b = {os, WtI + (size_t)(l * 2 + 1) * 128 * 256, inter_b + (size_t)(l * 2 + 1) * 128,
                   nullptr, nullptr, xs, NS, 256, 128, 128};
            P.blocksA = mbJ;
            k_mgemm<2><<<dim3(mbJ + mbS, 1), 256, 0, stream>>>(P);
        }
    }

    // final projection + scores
    {
        GPair P;
        P.a = {xj, WtJf, bjf, nullptr, nullptr, job_emb, NJ, 128, 128, 128};
        P.b = P.a;
        P.blocksA = mbJ;
        k_mgemm<1><<<dim3(mbJ, 1), 256, 0, stream>>>(P);
    }
    k_qvec<<<1, 128, 0, stream>>>(query, Wq, bq, qv);
    k_scores<<<cdiv(NJ, 4), 256, 0, stream>>>(job_emb, qv, scores, NJ);
}

// Round 6
// 468.459 us; speedup vs baseline: 1.9392x; 1.9392x over previous
//
#include <hip/hip_runtime.h>
#include <hip/hip_bf16.h>
#include <math.h>

#define NJ 30000
#define NS 12000
#define E_JS 300000
#define E_SJ 300000
#define E_SS 150000
#define ETOT (E_JS + E_SJ + E_SS + NS)   // 762000 incl. ss self loops
#define NBINS (NS + NJ + NS)             // 54000 combined dst bins
#define NBUK ((NBINS + 63) / 64)         // 844 coarse buckets (64 bins each)
#define SBERT 384
#define HIDDEN 128
#define OUTD 128
#define HIST_NB 128
#define SCAT_NB 120

static inline int cdiv(int a, int b) { return (a + b - 1) / b; }

typedef __attribute__((ext_vector_type(8))) short bf8_t;
typedef __attribute__((ext_vector_type(4))) float f4_t;
typedef unsigned short u16;

__device__ inline float bf2f(unsigned short u) {
    union { unsigned int i; float f; } z; z.i = ((unsigned int)u) << 16; return z.f;
}
__device__ inline unsigned short f2bf(float f) {
    unsigned int x = __float_as_uint(f);
    unsigned int r = (x + 0x7fffu + ((x >> 16) & 1u)) >> 16;   // RNE
    return (unsigned short)r;
}

// ---------------------------------------------------------------------------
// cast fp32 x_job/x_skill -> bf16
// ---------------------------------------------------------------------------
__global__ void k_cast_x(const float* __restrict__ xj, const float* __restrict__ xs,
                         unsigned short* __restrict__ oj, unsigned short* __restrict__ os) {
    const int NJE = NJ * SBERT;
    const int TOT = (NJ + NS) * SBERT;
    int i4 = (blockIdx.x * 256 + threadIdx.x) * 4;
    if (i4 >= TOT) return;
    const float* src; unsigned short* dst; int off;
    if (i4 < NJE) { src = xj; dst = oj; off = i4; }
    else { src = xs; dst = os; off = i4 - NJE; }
    float4 v = *(const float4*)&src[off];
    ushort4 o; o.x = f2bf(v.x); o.y = f2bf(v.y); o.z = f2bf(v.z); o.w = f2bf(v.w);
    *(ushort4*)&dst[off] = o;
}

// ---------------------------------------------------------------------------
// batched weight transpose+cast: dst[n*K+k] = (bf16)src[k*N+n]
// ---------------------------------------------------------------------------
struct CastT { const float* src; unsigned short* dst; int K; int N; };
struct CastTList { CastT m[13]; };

__global__ void k_castT(CastTList L) {
    CastT c = L.m[blockIdx.y];
    int idx = blockIdx.x * 256 + threadIdx.x;
    int total = c.K * c.N;
    if (idx >= total) return;
    int n = idx / c.K, k = idx % c.K;
    c.dst[idx] = f2bf(c.src[(size_t)k * c.N + n]);
}

// ---------------------------------------------------------------------------
// Precompute ws_a / wd_a (+ zero the bucket counters for the CSR build)
// ---------------------------------------------------------------------------
__global__ void k_wa(const float* __restrict__ Ws, const float* __restrict__ as,
                     const float* __restrict__ Wd, const float* __restrict__ ad,
                     float* __restrict__ wsa, float* __restrict__ wda,
                     int* __restrict__ bcnt) {
    int id = blockIdx.x * 256 + threadIdx.x;   // 2 * 1536 total
    if (id < NBUK) bcnt[id] = 0;
    if (id >= 2 * 1536) return;
    int which = id / 1536;
    int r = id % 1536;
    int lr = r / 256;       // 0..5  (l*3 + rel)
    int kh = r % 256;
    int k = kh / 2, h = kh % 2;
    const float* W = which ? Wd : Ws;
    const float* a = which ? ad : as;
    const float* wrow = W + ((size_t)(lr * 128 + k)) * 256 + h * 128;
    const float* arow = a + (size_t)(lr * 2 + h) * 128;
    float acc = 0.f;
    for (int c = 0; c < 128; ++c) acc += wrow[c] * arow[c];
    (which ? wda : wsa)[lr * 256 + k * 2 + h] = acc;
}

// ---------------------------------------------------------------------------
// Batched bf16 MFMA GEMM: up to 2 jobs per dispatch (unchanged from round 5)
// ---------------------------------------------------------------------------
struct GJob {
    const unsigned short* X; const unsigned short* Wt;
    const float* bias; const float* gamma; const float* beta;
    void* Y; int M; int K; int N; int ldY;
};
struct GPair { GJob a; GJob b; int blocksA; };

template <int EPI>
__global__ __launch_bounds__(256) void k_mgemm(GPair P) {
    int mb = blockIdx.x;
    GJob g = (mb < P.blocksA) ? P.a : P.b;
    if (mb >= P.blocksA) mb -= P.blocksA;
    const int n0 = blockIdx.y * 128;
    if (n0 >= g.N) return;
    const int row0 = mb * 64;

    __shared__ __align__(16) unsigned short Al[64][40];
    __shared__ __align__(16) unsigned short Bl[128][40];
    const int t = threadIdx.x;
    const int wave = t >> 6, lane = t & 63;
    const int q = lane >> 4, c = lane & 15;
    const int K = g.K;

    f4_t acc[8];
#pragma unroll
    for (int nt = 0; nt < 8; ++nt) acc[nt] = (f4_t){0.f, 0.f, 0.f, 0.f};

    for (int k0 = 0; k0 < K; k0 += 32) {
#pragma unroll
        for (int it = 0; it < 3; ++it) {
            int idx = t + it * 256;          // 768 chunks: 64 A rows + 128 B rows, 4x16B
            int r = idx >> 2, cc = (idx & 3) * 8;
            if (r < 64) {
                int gr = row0 + r;
                uint4 va = (gr < g.M) ? *(const uint4*)&g.X[(size_t)gr * K + k0 + cc]
                                      : make_uint4(0u, 0u, 0u, 0u);
                *(uint4*)&Al[r][cc] = va;
            } else {
                int br = r - 64;
                *(uint4*)&Bl[br][cc] = *(const uint4*)&g.Wt[(size_t)(n0 + br) * K + k0 + cc];
            }
        }
        __syncthreads();
        bf8_t af = *(const bf8_t*)&Al[wave * 16 + c][q * 8];
#pragma unroll
        for (int nt = 0; nt < 8; ++nt) {
            bf8_t bfr = *(const bf8_t*)&Bl[nt * 16 + c][q * 8];
            acc[nt] = __builtin_amdgcn_mfma_f32_16x16x32_bf16(af, bfr, acc[nt], 0, 0, 0);
        }
        __syncthreads();
    }

    float bcol[8], gcol[8], becol[8];
#pragma unroll
    for (int nt = 0; nt < 8; ++nt) {
        bcol[nt] = (EPI >= 1) ? g.bias[n0 + nt * 16 + c] : 0.f;
        if constexpr (EPI == 3) {
            gcol[nt] = g.gamma[nt * 16 + c];
            becol[nt] = g.beta[nt * 16 + c];
        }
    }

#pragma unroll
    for (int r = 0; r < 4; ++r) {
        int grow = row0 + wave * 16 + q * 4 + r;
        float v[8];
#pragma unroll
        for (int nt = 0; nt < 8; ++nt) v[nt] = acc[nt][r] + bcol[nt];
        if constexpr (EPI == 3) {
            float s = 0.f, ss = 0.f;
#pragma unroll
            for (int nt = 0; nt < 8; ++nt) { s += v[nt]; ss += v[nt] * v[nt]; }
#pragma unroll
            for (int m = 8; m >= 1; m >>= 1) {
                s += __shfl_xor(s, m, 64);
                ss += __shfl_xor(ss, m, 64);
            }
            float mu = s * (1.f / 128.f);
            float var = ss * (1.f / 128.f) - mu * mu;
            float rs = rsqrtf(var + 1e-5f);
#pragma unroll
            for (int nt = 0; nt < 8; ++nt)
                v[nt] = fmaxf((v[nt] - mu) * rs * gcol[nt] + becol[nt], 0.f);
        } else if constexpr (EPI == 2) {
#pragma unroll
            for (int nt = 0; nt < 8; ++nt) v[nt] = fmaxf(v[nt], 0.f);
        }
        if (grow < g.M) {
            if constexpr (EPI == 1) {
                float* Y = (float*)g.Y;
#pragma unroll
                for (int nt = 0; nt < 8; ++nt)
                    Y[(size_t)grow * g.ldY + n0 + nt * 16 + c] = v[nt];
            } else {
                unsigned short* Y = (unsigned short*)g.Y;
#pragma unroll
                for (int nt = 0; nt < 8; ++nt)
                    Y[(size_t)grow * g.ldY + n0 + nt * 16 + c] = f2bf(v[nt]);
            }
        }
    }
}

// ---------------------------------------------------------------------------
// Per-layer alpha precompute (unchanged)
// ---------------------------------------------------------------------------
__global__ __launch_bounds__(256) void k_alpha_all(
    const unsigned short* __restrict__ xj, const unsigned short* __restrict__ xs,
    const float* __restrict__ wsa, const float* __restrict__ wda, int l3,
    float* __restrict__ aJ, float* __restrict__ aS) {
    int wave = threadIdx.x >> 6, lane = threadIdx.x & 63;
    int node = blockIdx.x * 4 + wave;
    if (node < NJ) {
        ushort2 xv = *(const ushort2*)&xj[(size_t)node * 128 + lane * 2];
        float x0 = bf2f(xv.x), x1 = bf2f(xv.y);
        float4 w0 = *(const float4*)&wsa[(size_t)(l3 + 0) * 256 + lane * 4];
        float4 w1 = *(const float4*)&wda[(size_t)(l3 + 1) * 256 + lane * 4];
        float p0 = x0 * w0.x + x1 * w0.z, p1 = x0 * w0.y + x1 * w0.w;
        float p2 = x0 * w1.x + x1 * w1.z, p3 = x0 * w1.y + x1 * w1.w;
#pragma unroll
        for (int m = 32; m >= 1; m >>= 1) {
            p0 += __shfl_xor(p0, m, 64); p1 += __shfl_xor(p1, m, 64);
            p2 += __shfl_xor(p2, m, 64); p3 += __shfl_xor(p3, m, 64);
        }
        if (lane == 0) {
            float4* o = (float4*)&aJ[(size_t)node * 4];
            *o = make_float4(p0, p1, p2, p3);
        }
    } else if (node < NJ + NS) {
        int n = node - NJ;
        ushort2 xv = *(const ushort2*)&xs[(size_t)n * 128 + lane * 2];
        float x0 = bf2f(xv.x), x1 = bf2f(xv.y);
        float4 wA = *(const float4*)&wsa[(size_t)(l3 + 2) * 256 + lane * 4];  // as ss
        float4 wB = *(const float4*)&wda[(size_t)(l3 + 0) * 256 + lane * 4];  // ad js
        float4 wC = *(const float4*)&wsa[(size_t)(l3 + 1) * 256 + lane * 4];  // as sj
        float4 wD = *(const float4*)&wda[(size_t)(l3 + 2) * 256 + lane * 4];  // ad ss
        float p0 = x0 * wA.x + x1 * wA.z, p1 = x0 * wA.y + x1 * wA.w;
        float p2 = x0 * wB.x + x1 * wB.z, p3 = x0 * wB.y + x1 * wB.w;
        float p4 = x0 * wC.x + x1 * wC.z, p5 = x0 * wC.y + x1 * wC.w;
        float p6 = x0 * wD.x + x1 * wD.z, p7 = x0 * wD.y + x1 * wD.w;
#pragma unroll
        for (int m = 32; m >= 1; m >>= 1) {
            p0 += __shfl_xor(p0, m, 64); p1 += __shfl_xor(p1, m, 64);
            p2 += __shfl_xor(p2, m, 64); p3 += __shfl_xor(p3, m, 64);
            p4 += __shfl_xor(p4, m, 64); p5 += __shfl_xor(p5, m, 64);
            p6 += __shfl_xor(p6, m, 64); p7 += __shfl_xor(p7, m, 64);
        }
        if (lane == 0) {
            float4* o = (float4*)&aS[(size_t)n * 8];
            o[0] = make_float4(p0, p1, p2, p3);
            o[1] = make_float4(p4, p5, p6, p7);
        }
    }
}

// ---------------------------------------------------------------------------
// Two-level bucketed CSR build, LDS-aggregated atomics.
// bin layout: [0,NS) js | [NS,NS+NJ) sj | [NS+NJ,NBINS) ss (incl self loops)
// bucket = bin >> 6 (NBUK buckets of 64 bins)
// ---------------------------------------------------------------------------
__device__ inline void edge_decode(int e, const int* js_src, const int* js_dst,
                                   const int* sj_src, const int* sj_dst,
                                   const int* ss_src, const int* ss_dst,
                                   int& src, int& bin) {
    if (e < E_JS) { src = js_src[e]; bin = js_dst[e]; }
    else if (e < E_JS + E_SJ) { int i = e - E_JS; src = sj_src[i]; bin = NS + sj_dst[i]; }
    else if (e < E_JS + E_SJ + E_SS) { int i = e - E_JS - E_SJ; src = ss_src[i]; bin = NS + NJ + ss_dst[i]; }
    else { int i = e - E_JS - E_SJ - E_SS; src = i; bin = NS + NJ + i; }
}

// LDS-aggregated bucket histogram: <=NBUK global atomics per block
__global__ __launch_bounds__(1024) void k_bucket_hist(
    const int* __restrict__ js_src, const int* __restrict__ js_dst,
    const int* __restrict__ sj_src, const int* __restrict__ sj_dst,
    const int* __restrict__ ss_src, const int* __restrict__ ss_dst,
    int* __restrict__ bcnt) {
    __shared__ int lh[NBUK];
    for (int i = threadIdx.x; i < NBUK; i += 1024) lh[i] = 0;
    __syncthreads();
    for (int e = blockIdx.x * 1024 + threadIdx.x; e < ETOT; e += gridDim.x * 1024) {
        int src, bin;
        edge_decode(e, js_src, js_dst, sj_src, sj_dst, ss_src, ss_dst, src, bin);
        atomicAdd(&lh[bin >> 6], 1);
    }
    __syncthreads();
    for (int i = threadIdx.x; i < NBUK; i += 1024) {
        int v = lh[i];
        if (v) atomicAdd(&bcnt[i], v);
    }
}

__global__ void k_bucket_scan(const int* __restrict__ bcnt, int* __restrict__ bukoff,
                              int* __restrict__ bukcur) {
    __shared__ int sd[1024];
    int t = threadIdx.x;
    int v = (t < NBUK) ? bcnt[t] : 0;
    sd[t] = v;
    __syncthreads();
    for (int off = 1; off < 1024; off <<= 1) {
        int tmp = (t >= off) ? sd[t - off] : 0;
        __syncthreads();
        sd[t] += tmp;
        __syncthreads();
    }
    if (t < NBUK) { int ex = sd[t] - v; bukoff[t] = ex; bukcur[t] = ex; }
    if (t == 0) bukoff[NBUK] = ETOT;
}

// per-block: LDS hist -> one range-reservation atomic per touched bucket ->
// scatter via LDS cursors. Contiguous chunk per block for locality.
__global__ __launch_bounds__(1024) void k_scatter_pairs(
    const int* __restrict__ js_src, const int* __restrict__ js_dst,
    const int* __restrict__ sj_src, const int* __restrict__ sj_dst,
    const int* __restrict__ ss_src, const int* __restrict__ ss_dst,
    int* __restrict__ bukcur, uint2* __restrict__ pairs) {
    __shared__ int lh[NBUK];
    __shared__ int lbase[NBUK];
    const int CH = (ETOT + (int)gridDim.x - 1) / (int)gridDim.x;
    const int beg = blockIdx.x * CH;
    const int endi = (beg + CH < ETOT) ? beg + CH : ETOT;
    for (int i = threadIdx.x; i < NBUK; i += 1024) lh[i] = 0;
    __syncthreads();
    for (int e = beg + threadIdx.x; e < endi; e += 1024) {
        int src, bin;
        edge_decode(e, js_src, js_dst, sj_src, sj_dst, ss_src, ss_dst, src, bin);
        atomicAdd(&lh[bin >> 6], 1);
    }
    __syncthreads();
    for (int i = threadIdx.x; i < NBUK; i += 1024) {
        int v = lh[i];
        lbase[i] = v ? atomicAdd(&bukcur[i], v) : 0;
    }
    __syncthreads();
    for (int i = threadIdx.x; i < NBUK; i += 1024) lh[i] = 0;
    __syncthreads();
    for (int e = beg + threadIdx.x; e < endi; e += 1024) {
        int src, bin;
        edge_decode(e, js_src, js_dst, sj_src, sj_dst, ss_src, ss_dst, src, bin);
        int bu = bin >> 6;
        int pos = lbase[bu] + atomicAdd(&lh[bu], 1);
        pairs[pos] = make_uint2((unsigned)src, (unsigned)bin);
    }
}

// one block per bucket: local 64-bin CSR in LDS, dense contiguous esrc writes
__global__ __launch_bounds__(256) void k_finalize(
    const uint2* __restrict__ pairs, const int* __restrict__ bukoff,
    int* __restrict__ offs, int* __restrict__ esrc) {
    int b = blockIdx.x, t = threadIdx.x;
    int base = bukoff[b], endi = bukoff[b + 1];
    __shared__ int cnt[64], excl[64], curs[64];
    if (t < 64) cnt[t] = 0;
    __syncthreads();
    for (int i = base + t; i < endi; i += 256)
        atomicAdd(&cnt[pairs[i].y & 63], 1);
    __syncthreads();
    if (t < 64) {
        int v = cnt[t];
        int inc = v;
#pragma unroll
        for (int off = 1; off < 64; off <<= 1) {
            int tmp = __shfl_up(inc, off, 64);
            if (t >= off) inc += tmp;
        }
        excl[t] = inc - v;
        curs[t] = inc - v;
    }
    __syncthreads();
    for (int i = base + t; i < endi; i += 256) {
        uint2 p = pairs[i];
        int lb = p.y & 63;
        int pos = atomicAdd(&curs[lb], 1);
        esrc[base + pos] = (int)p.x;
    }
    if (t < 64) {
        int bin = b * 64 + t;
        if (bin < NBINS) offs[bin] = base + excl[t];
    }
    if (b == 0 && t == 0) offs[NBINS] = ETOT;
}

// ---------------------------------------------------------------------------
// Fused gather + edge softmax, 4-way unrolled edge loop (clamped tail).
// ---------------------------------------------------------------------------
__global__ __launch_bounds__(256) void k_gather(
    const int* __restrict__ offs, const int* __restrict__ esrc,
    const float* __restrict__ aS, int sStride,
    const float* __restrict__ aD, int dStride,
    const unsigned short* __restrict__ hs, int hsLd,
    const float* __restrict__ bias,
    unsigned short* __restrict__ out, int Nd, int accumulate) {
    int wave = threadIdx.x >> 6, lane = threadIdx.x & 63;
    int d = blockIdx.x * 4 + wave;
    if (d >= Nd) return;
    int c = lane * 4;
    int h = (c >= 128) ? 1 : 0;
    float ad = aD[(size_t)d * dStride + h];
    int beg = offs[d], end = offs[d + 1];
    float ax = 0.f, ay = 0.f, az = 0.f, aw = 0.f, den = 0.f;
    for (int j = beg; j < end; j += 4) {
        int j1 = j + 1 < end ? j + 1 : end - 1;
        int j2 = j + 2 < end ? j + 2 : end - 1;
        int j3 = j + 3 < end ? j + 3 : end - 1;
        int s0 = esrc[j], s1 = esrc[j1], s2 = esrc[j2], s3 = esrc[j3];
        float as0 = aS[(size_t)s0 * sStride + h];
        float as1 = aS[(size_t)s1 * sStride + h];
        float as2 = aS[(size_t)s2 * sStride + h];
        float as3 = aS[(size_t)s3 * sStride + h];
        ushort4 v0 = *(const ushort4*)&hs[(size_t)s0 * hsLd + c];
        ushort4 v1 = *(const ushort4*)&hs[(size_t)s1 * hsLd + c];
        ushort4 v2 = *(const ushort4*)&hs[(size_t)s2 * hsLd + c];
        ushort4 v3 = *(const ushort4*)&hs[(size_t)s3 * hsLd + c];
        float e0 = as0 + ad; e0 = e0 > 0.f ? e0 : 0.2f * e0;
        float e1 = as1 + ad; e1 = e1 > 0.f ? e1 : 0.2f * e1;
        float e2 = as2 + ad; e2 = e2 > 0.f ? e2 : 0.2f * e2;
        float e3 = as3 + ad; e3 = e3 > 0.f ? e3 : 0.2f * e3;
        float p0 = __expf(e0);
        float p1 = (j + 1 < end) ? __expf(e1) : 0.f;
        float p2 = (j + 2 < end) ? __expf(e2) : 0.f;
        float p3 = (j + 3 < end) ? __expf(e3) : 0.f;
        ax += p0 * bf2f(v0.x) + p1 * bf2f(v1.x) + p2 * bf2f(v2.x) + p3 * bf2f(v3.x);
        ay += p0 * bf2f(v0.y) + p1 * bf2f(v1.y) + p2 * bf2f(v2.y) + p3 * bf2f(v3.y);
        az += p0 * bf2f(v0.z) + p1 * bf2f(v1.z) + p2 * bf2f(v2.z) + p3 * bf2f(v3.z);
        aw += p0 * bf2f(v0.w) + p1 * bf2f(v1.w) + p2 * bf2f(v2.w) + p3 * bf2f(v3.w);
        den += p0 + p1 + p2 + p3;
    }
    float sc = 1.f / (den + 1e-16f);
    float4 b4 = *(const float4*)&bias[c];
    unsigned short* op = &out[(size_t)d * 256 + c];
    float o0 = ax * sc + b4.x, o1 = ay * sc + b4.y;
    float o2 = az * sc + b4.z, o3 = aw * sc + b4.w;
    if (accumulate) {
        ushort4 prev = *(ushort4*)op;
        o0 += bf2f(prev.x); o1 += bf2f(prev.y); o2 += bf2f(prev.z); o3 += bf2f(prev.w);
    }
    ushort4 o; o.x = f2bf(o0); o.y = f2bf(o1); o.z = f2bf(o2); o.w = f2bf(o3);
    *(ushort4*)op = o;
}

// ---------------------------------------------------------------------------
// q = query @ Wq + bq  (fp32)
// ---------------------------------------------------------------------------
__global__ void k_qvec(const float* __restrict__ query, const float* __restrict__ Wq,
                       const float* __restrict__ bq, float* __restrict__ qv) {
    int c = threadIdx.x;  // 128
    float acc = bq[c];
    for (int k = 0; k < SBERT; ++k) acc += query[k] * Wq[(size_t)k * 128 + c];
    qv[c] = acc;
}

// scores[r] = job_emb[r] . q   (wave per row, job_emb fp32)
__global__ __launch_bounds__(256) void k_scores(const float* __restrict__ jemb,
                                                const float* __restrict__ q,
                                                float* __restrict__ sc, int n) {
    int wave = threadIdx.x >> 6, lane = threadIdx.x & 63;
    int r = blockIdx.x * 4 + wave;
    if (r >= n) return;
    float2 a = *(const float2*)&jemb[(size_t)r * 128 + lane * 2];
    float2 b = *(const float2*)&q[lane * 2];
    float p = a.x * b.x + a.y * b.y;
#pragma unroll
    for (int m = 32; m >= 1; m >>= 1) p += __shfl_xor(p, m, 64);
    if (lane == 0) sc[r] = p;
}

// ---------------------------------------------------------------------------
extern "C" void kernel_launch(void* const* d_in, const int* in_sizes, int n_in,
                              void* d_out, int out_size, void* d_ws, size_t ws_size,
                              hipStream_t stream) {
    const float* x_job   = (const float*)d_in[0];
    const float* x_skill = (const float*)d_in[1];
    const int* js_src = (const int*)d_in[2];
    const int* js_dst = (const int*)d_in[3];
    const int* sj_src = (const int*)d_in[4];
    const int* sj_dst = (const int*)d_in[5];
    const int* ss_src = (const int*)d_in[6];
    const int* ss_dst = (const int*)d_in[7];
    const float* query    = (const float*)d_in[8];
    const float* W0_job   = (const float*)d_in[9];
    const float* b0_job   = (const float*)d_in[10];
    const float* g0_job   = (const float*)d_in[11];
    const float* be0_job  = (const float*)d_in[12];
    const float* W0_skill = (const float*)d_in[13];
    const float* b0_skill = (const float*)d_in[14];
    const float* g0_skill = (const float*)d_in[15];
    const float* be0_skill= (const float*)d_in[16];
    const float* gat_Ws = (const float*)d_in[17];
    const float* gat_Wd = (const float*)d_in[18];
    const float* gat_as = (const float*)d_in[19];
    const float* gat_ad = (const float*)d_in[20];
    const float* gat_b  = (const float*)d_in[21];
    const float* inter_W = (const float*)d_in[22];
    const float* inter_b = (const float*)d_in[23];
    const float* Wjf = (const float*)d_in[24];
    const float* bjf = (const float*)d_in[25];
    const float* Wq  = (const float*)d_in[26];
    const float* bq  = (const float*)d_in[27];

    // workspace carve (256B aligned bump allocator)
    char* w = (char*)d_ws;
    auto alloc = [&](size_t bytes) -> void* {
        void* p = (void*)w;
        w += (bytes + 255) & ~(size_t)255;
        return p;
    };
    u16* xjob_b   = (u16*)alloc((size_t)NJ * SBERT * 2);
    u16* xskill_b = (u16*)alloc((size_t)NS * SBERT * 2);
    u16* xj  = (u16*)alloc((size_t)NJ * 128 * 2);
    u16* xs  = (u16*)alloc((size_t)NS * 128 * 2);
    u16* hs1 = (u16*)alloc((size_t)NJ * 256 * 2);   // job-side projection (js)
    u16* hs2 = (u16*)alloc((size_t)NS * 512 * 2);   // skill-side: [sj | ss]
    u16* oj  = (u16*)alloc((size_t)NJ * 256 * 2);
    u16* os  = (u16*)alloc((size_t)NS * 256 * 2);
    // transposed bf16 weights
    u16* WtW0j = (u16*)alloc((size_t)SBERT * 128 * 2);
    u16* WtW0s = (u16*)alloc((size_t)SBERT * 128 * 2);
    u16* WtWs  = (u16*)alloc((size_t)6 * 128 * 256 * 2);   // [lr][256][128]
    u16* WtI   = (u16*)alloc((size_t)4 * 256 * 128 * 2);   // [i][128][256]
    u16* WtJf  = (u16*)alloc((size_t)128 * 128 * 2);
    float* aJ = (float*)alloc((size_t)NJ * 4 * 4);
    float* aS = (float*)alloc((size_t)NS * 8 * 4);
    float* wsa = (float*)alloc(6 * 256 * 4);
    float* wda = (float*)alloc(6 * 256 * 4);
    int* bcnt   = (int*)alloc((size_t)NBUK * 4);
    int* bukoff = (int*)alloc((size_t)(NBUK + 1) * 4);
    int* bukcur = (int*)alloc((size_t)NBUK * 4);
    uint2* pairs = (uint2*)alloc((size_t)ETOT * 8);
    int* offs = (int*)alloc((size_t)(NBINS + 1) * 4);
    int* esrc = (int*)alloc((size_t)ETOT * 4);

    float* out = (float*)d_out;
    float* scores  = out;
    float* job_emb = out + NJ;
    float* qv      = out + NJ + (size_t)NJ * 128;

    const int mbJ = cdiv(NJ, 64);   // 469
    const int mbS = cdiv(NS, 64);   // 188

    // --- casts: x -> bf16, weights -> transposed bf16 ---
    {
        int tot4 = (NJ + NS) * SBERT / 4;
        k_cast_x<<<cdiv(tot4, 256), 256, 0, stream>>>(x_job, x_skill, xjob_b, xskill_b);
        CastTList L;
        L.m[0] = {W0_job, WtW0j, SBERT, 128};
        L.m[1] = {W0_skill, WtW0s, SBERT, 128};
        for (int lr = 0; lr < 6; ++lr)
            L.m[2 + lr] = {gat_Ws + (size_t)lr * 128 * 256, WtWs + (size_t)lr * 256 * 128, 128, 256};
        for (int i = 0; i < 4; ++i)
            L.m[8 + i] = {inter_W + (size_t)i * 256 * 128, WtI + (size_t)i * 128 * 256, 256, 128};
        L.m[12] = {Wjf, WtJf, 128, 128};
        k_castT<<<dim3(cdiv(SBERT * 128, 256), 13), 256, 0, stream>>>(L);
    }

    // --- precompute attention weight vectors (+ zero bucket counters) ---
    k_wa<<<cdiv(2 * 1536, 256), 256, 0, stream>>>(gat_Ws, gat_as, gat_Wd, gat_ad, wsa, wda, bcnt);

    // --- bucketed CSR build, LDS-aggregated atomics (layer-invariant) ---
    k_bucket_hist<<<HIST_NB, 1024, 0, stream>>>(js_src, js_dst, sj_src, sj_dst,
                                                ss_src, ss_dst, bcnt);
    k_bucket_scan<<<1, 1024, 0, stream>>>(bcnt, bukoff, bukcur);
    k_scatter_pairs<<<SCAT_NB, 1024, 0, stream>>>(js_src, js_dst, sj_src, sj_dst,
                                                  ss_src, ss_dst, bukcur, pairs);
    k_finalize<<<NBUK, 256, 0, stream>>>(pairs, bukoff, offs, esrc);

    // --- initial linear + LN + relu (batched job+skill) ---
    {
        GPair P;
        P.a = {xjob_b, WtW0j, b0_job, g0_job, be0_job, xj, NJ, SBERT, 128, 128};
        P.b = {xskill_b, WtW0s, b0_skill, g0_skill, be0_skill, xs, NS, SBERT, 128, 128};
        P.blocksA = mbJ;
        k_mgemm<3><<<dim3(mbJ + mbS, 1), 256, 0, stream>>>(P);
    }

    for (int l = 0; l < 2; ++l) {
        int l3 = l * 3;
        k_alpha_all<<<cdiv(NJ + NS, 4), 256, 0, stream>>>(xj, xs, wsa, wda, l3, aJ, aS);

        // projections: hs1 = xj @ Ws[js] (N=256); hs2 = xs @ [Ws[sj]|Ws[ss]] (N=512)
        {
            GPair P;
            P.a = {xj, WtWs + (size_t)(l3 + 0) * 256 * 128, nullptr, nullptr, nullptr,
                   hs1, NJ, 128, 256, 256};
            P.b = {xs, WtWs + (size_t)(l3 + 1) * 256 * 128, nullptr, nullptr, nullptr,
                   hs2, NS, 128, 512, 512};
            P.blocksA = mbJ;
            k_mgemm<0><<<dim3(mbJ + mbS, 4), 256, 0, stream>>>(P);
        }

        // o_s = GAT_js(xj->xs) + GAT_ss(xs->xs)
        k_gather<<<cdiv(NS, 4), 256, 0, stream>>>(
            offs, esrc, aJ + 0, 4, aS + 2, 8, hs1, 256,
            gat_b + (size_t)(l3 + 0) * 256, os, NS, 0);
        k_gather<<<cdiv(NS, 4), 256, 0, stream>>>(
            offs + NS + NJ, esrc, aS + 0, 8, aS + 6, 8, hs2 + 256, 512,
            gat_b + (size_t)(l3 + 2) * 256, os, NS, 1);
        // o_j = GAT_sj(xs->xj)
        k_gather<<<cdiv(NJ, 4), 256, 0, stream>>>(
            offs + NS, esrc, aS + 4, 8, aJ + 2, 4, hs2, 512,
            gat_b + (size_t)(l3 + 1) * 256, oj, NJ, 0);

        // inter linears + relu (batched job+skill, overwrite xj, xs)
        {
            GPair P;
            P.a = {oj, WtI + (size_t)(l * 2 + 0) * 128 * 256, inter_b + (size_t)(l * 2 + 0) * 128,
                   nullptr, nullptr, xj, NJ, 256, 128, 128};
            P.b = {os, WtI + (size_t)(l * 2 + 1) * 128 * 256, inter_b + (size_t)(l * 2 + 1) * 128,
                   nullptr, nullptr, xs, NS, 256, 128, 128};
            P.blocksA = mbJ;
            k_mgemm<2><<<dim3(mbJ + mbS, 1), 256, 0, stream>>>(P);
        }
    }

    // final projection + scores
    {
        GPair P;
        P.a = {xj, WtJf, bjf, nullptr, nullptr, job_emb, NJ, 128, 128, 128};
        P.b = P.a;
        P.blocksA = mbJ;
        k_mgemm<1><<<dim3(mbJ, 1), 256, 0, stream>>>(P);
    }
    k_qvec<<<1, 128, 0, stream>>>(query, Wq, bq, qv);
    k_scores<<<cdiv(NJ, 4), 256, 0, stream>>>(job_emb, qv, scores, NJ);
}

// Round 7
// 411.281 us; speedup vs baseline: 2.2088x; 1.1390x over previous
//
#include <hip/hip_runtime.h>
#include <hip/hip_bf16.h>
#include <math.h>

#define NJ 30000
#define NS 12000
#define E_JS 300000
#define E_SJ 300000
#define E_SS 150000
#define ETOT (E_JS + E_SJ + E_SS + NS)   // 762000 incl. ss self loops
#define NBINS (NS + NJ + NS)             // 54000 combined dst bins
#define NBUK ((NBINS + 63) / 64)         // 844 coarse buckets (64 bins each)
#define SBERT 384
#define HIDDEN 128
#define OUTD 128
#define HIST_NB 128
#define SCAT_NB 120

static inline int cdiv(int a, int b) { return (a + b - 1) / b; }

typedef __attribute__((ext_vector_type(8))) short bf8_t;
typedef __attribute__((ext_vector_type(4))) float f4_t;
typedef unsigned short u16;

__device__ inline float bf2f(unsigned short u) {
    union { unsigned int i; float f; } z; z.i = ((unsigned int)u) << 16; return z.f;
}
__device__ inline unsigned short f2bf(float f) {
    unsigned int x = __float_as_uint(f);
    unsigned int r = (x + 0x7fffu + ((x >> 16) & 1u)) >> 16;   // RNE
    return (unsigned short)r;
}

// ---------------------------------------------------------------------------
// k_prep: one dispatch for (a) 13 weight transpose+casts, (b) wa precompute
// + bcnt zero, (c) qv = query @ Wq + bq.
// block ranges: [0,2496) castT  [2496,2508) wa  [2508] qvec
// ---------------------------------------------------------------------------
struct CastT { const float* src; unsigned short* dst; int K; int N; };
struct PrepArgs {
    CastT m[13];
    const float* Ws; const float* as_; const float* Wd; const float* ad_;
    float* wsa; float* wda; int* bcnt;
    const float* query; const float* Wq; const float* bq; float* qv;
};

__global__ __launch_bounds__(256) void k_prep(PrepArgs A) {
    int b = blockIdx.x;
    if (b < 2496) {                     // castT: 13 mats x 192 blocks
        int mi = b / 192, bx = b % 192;
        CastT c = A.m[mi];
        int idx = bx * 256 + threadIdx.x;
        if (idx < c.K * c.N) {
            int n = idx / c.K, k = idx % c.K;
            c.dst[idx] = f2bf(c.src[(size_t)k * c.N + n]);
        }
    } else if (b < 2508) {              // wa: 12 blocks (3072 ids)
        int id = (b - 2496) * 256 + threadIdx.x;
        if (id < NBUK) A.bcnt[id] = 0;
        if (id >= 2 * 1536) return;
        int which = id / 1536;
        int r = id % 1536;
        int lr = r / 256;
        int kh = r % 256;
        int k = kh / 2, h = kh % 2;
        const float* W = which ? A.Wd : A.Ws;
        const float* a = which ? A.ad_ : A.as_;
        const float* wrow = W + ((size_t)(lr * 128 + k)) * 256 + h * 128;
        const float* arow = a + (size_t)(lr * 2 + h) * 128;
        float acc = 0.f;
        for (int c2 = 0; c2 < 128; ++c2) acc += wrow[c2] * arow[c2];
        (which ? A.wda : A.wsa)[lr * 256 + k * 2 + h] = acc;
    } else {                            // qvec: 1 block, 128 threads
        int c = threadIdx.x;
        if (c < 128) {
            float acc = A.bq[c];
            for (int k = 0; k < SBERT; ++k) acc += A.query[k] * A.Wq[(size_t)k * 128 + c];
            A.qv[c] = acc;
        }
    }
}

// ---------------------------------------------------------------------------
// Batched bf16 MFMA GEMM: up to 2 jobs per dispatch. BM=64.
//   srcf32: X is fp32, converted to bf16 during LDS staging.
//   EPI: 0 none->bf16, 1 +bias->fp32 (+fused scores), 2 +bias,relu->bf16,
//        3 +bias,LN,relu->bf16
// ---------------------------------------------------------------------------
struct GJob {
    const void* X; const unsigned short* Wt;
    const float* bias; const float* gamma; const float* beta;
    void* Y; int M; int K; int N; int ldY; int srcf32;
    const float* qv; float* sc;
};
struct GPair { GJob a; GJob b; int blocksA; };

template <int EPI>
__global__ __launch_bounds__(256) void k_mgemm(GPair P) {
    int mb = blockIdx.x;
    GJob g = (mb < P.blocksA) ? P.a : P.b;
    if (mb >= P.blocksA) mb -= P.blocksA;
    const int n0 = blockIdx.y * 128;
    if (n0 >= g.N) return;
    const int row0 = mb * 64;

    __shared__ __align__(16) unsigned short Al[64][40];
    __shared__ __align__(16) unsigned short Bl[128][40];
    const int t = threadIdx.x;
    const int wave = t >> 6, lane = t & 63;
    const int q = lane >> 4, c = lane & 15;
    const int K = g.K;

    f4_t acc[8];
#pragma unroll
    for (int nt = 0; nt < 8; ++nt) acc[nt] = (f4_t){0.f, 0.f, 0.f, 0.f};

    for (int k0 = 0; k0 < K; k0 += 32) {
#pragma unroll
        for (int it = 0; it < 3; ++it) {
            int idx = t + it * 256;          // 768 chunks: 64 A rows + 128 B rows, 4x(8 elems)
            int r = idx >> 2, cc = (idx & 3) * 8;
            if (r < 64) {
                int gr = row0 + r;
                if (g.srcf32) {
                    ushort4 lo = make_ushort4(0, 0, 0, 0), hi = lo;
                    if (gr < g.M) {
                        const float* Xf = (const float*)g.X;
                        const float* p = &Xf[(size_t)gr * K + k0 + cc];
                        float4 f0 = *(const float4*)p;
                        float4 f1 = *(const float4*)(p + 4);
                        lo = make_ushort4(f2bf(f0.x), f2bf(f0.y), f2bf(f0.z), f2bf(f0.w));
                        hi = make_ushort4(f2bf(f1.x), f2bf(f1.y), f2bf(f1.z), f2bf(f1.w));
                    }
                    *(ushort4*)&Al[r][cc] = lo;
                    *(ushort4*)&Al[r][cc + 4] = hi;
                } else {
                    const unsigned short* Xb = (const unsigned short*)g.X;
                    uint4 va = (gr < g.M) ? *(const uint4*)&Xb[(size_t)gr * K + k0 + cc]
                                          : make_uint4(0u, 0u, 0u, 0u);
                    *(uint4*)&Al[r][cc] = va;
                }
            } else {
                int br = r - 64;
                *(uint4*)&Bl[br][cc] = *(const uint4*)&g.Wt[(size_t)(n0 + br) * K + k0 + cc];
            }
        }
        __syncthreads();
        bf8_t af = *(const bf8_t*)&Al[wave * 16 + c][q * 8];
#pragma unroll
        for (int nt = 0; nt < 8; ++nt) {
            bf8_t bfr = *(const bf8_t*)&Bl[nt * 16 + c][q * 8];
            acc[nt] = __builtin_amdgcn_mfma_f32_16x16x32_bf16(af, bfr, acc[nt], 0, 0, 0);
        }
        __syncthreads();
    }

    float bcol[8], gcol[8], becol[8], qcol[8];
#pragma unroll
    for (int nt = 0; nt < 8; ++nt) {
        bcol[nt] = (EPI >= 1) ? g.bias[n0 + nt * 16 + c] : 0.f;
        if constexpr (EPI == 3) {
            gcol[nt] = g.gamma[nt * 16 + c];
            becol[nt] = g.beta[nt * 16 + c];
        }
        if constexpr (EPI == 1) qcol[nt] = g.qv[n0 + nt * 16 + c];
    }

#pragma unroll
    for (int r = 0; r < 4; ++r) {
        int grow = row0 + wave * 16 + q * 4 + r;
        float v[8];
#pragma unroll
        for (int nt = 0; nt < 8; ++nt) v[nt] = acc[nt][r] + bcol[nt];
        if constexpr (EPI == 3) {
            float s = 0.f, ss = 0.f;
#pragma unroll
            for (int nt = 0; nt < 8; ++nt) { s += v[nt]; ss += v[nt] * v[nt]; }
#pragma unroll
            for (int m = 8; m >= 1; m >>= 1) {
                s += __shfl_xor(s, m, 64);
                ss += __shfl_xor(ss, m, 64);
            }
            float mu = s * (1.f / 128.f);
            float var = ss * (1.f / 128.f) - mu * mu;
            float rs = rsqrtf(var + 1e-5f);
#pragma unroll
            for (int nt = 0; nt < 8; ++nt)
                v[nt] = fmaxf((v[nt] - mu) * rs * gcol[nt] + becol[nt], 0.f);
        } else if constexpr (EPI == 2) {
#pragma unroll
            for (int nt = 0; nt < 8; ++nt) v[nt] = fmaxf(v[nt], 0.f);
        }
        if constexpr (EPI == 1) {
            // fused scores: row . qv, reduce over the 16-lane c-group
            float part = 0.f;
#pragma unroll
            for (int nt = 0; nt < 8; ++nt) part += v[nt] * qcol[nt];
#pragma unroll
            for (int m = 8; m >= 1; m >>= 1) part += __shfl_xor(part, m, 64);
            if (c == 0 && grow < g.M) g.sc[grow] = part;
        }
        if (grow < g.M) {
            if constexpr (EPI == 1) {
                float* Y = (float*)g.Y;
#pragma unroll
                for (int nt = 0; nt < 8; ++nt)
                    Y[(size_t)grow * g.ldY + n0 + nt * 16 + c] = v[nt];
            } else {
                unsigned short* Y = (unsigned short*)g.Y;
#pragma unroll
                for (int nt = 0; nt < 8; ++nt)
                    Y[(size_t)grow * g.ldY + n0 + nt * 16 + c] = f2bf(v[nt]);
            }
        }
    }
}

// ---------------------------------------------------------------------------
// Per-layer alpha precompute
//   aJ[n][4] = {as_js(h0,h1), ad_sj(h0,h1)}
//   aS[n][8] = {as_ss(h0,h1), ad_js(h0,h1), as_sj(h0,h1), ad_ss(h0,h1)}
// ---------------------------------------------------------------------------
__global__ __launch_bounds__(256) void k_alpha_all(
    const unsigned short* __restrict__ xj, const unsigned short* __restrict__ xs,
    const float* __restrict__ wsa, const float* __restrict__ wda, int l3,
    float* __restrict__ aJ, float* __restrict__ aS) {
    int wave = threadIdx.x >> 6, lane = threadIdx.x & 63;
    int node = blockIdx.x * 4 + wave;
    if (node < NJ) {
        ushort2 xv = *(const ushort2*)&xj[(size_t)node * 128 + lane * 2];
        float x0 = bf2f(xv.x), x1 = bf2f(xv.y);
        float4 w0 = *(const float4*)&wsa[(size_t)(l3 + 0) * 256 + lane * 4];
        float4 w1 = *(const float4*)&wda[(size_t)(l3 + 1) * 256 + lane * 4];
        float p0 = x0 * w0.x + x1 * w0.z, p1 = x0 * w0.y + x1 * w0.w;
        float p2 = x0 * w1.x + x1 * w1.z, p3 = x0 * w1.y + x1 * w1.w;
#pragma unroll
        for (int m = 32; m >= 1; m >>= 1) {
            p0 += __shfl_xor(p0, m, 64); p1 += __shfl_xor(p1, m, 64);
            p2 += __shfl_xor(p2, m, 64); p3 += __shfl_xor(p3, m, 64);
        }
        if (lane == 0) {
            float4* o = (float4*)&aJ[(size_t)node * 4];
            *o = make_float4(p0, p1, p2, p3);
        }
    } else if (node < NJ + NS) {
        int n = node - NJ;
        ushort2 xv = *(const ushort2*)&xs[(size_t)n * 128 + lane * 2];
        float x0 = bf2f(xv.x), x1 = bf2f(xv.y);
        float4 wA = *(const float4*)&wsa[(size_t)(l3 + 2) * 256 + lane * 4];  // as ss
        float4 wB = *(const float4*)&wda[(size_t)(l3 + 0) * 256 + lane * 4];  // ad js
        float4 wC = *(const float4*)&wsa[(size_t)(l3 + 1) * 256 + lane * 4];  // as sj
        float4 wD = *(const float4*)&wda[(size_t)(l3 + 2) * 256 + lane * 4];  // ad ss
        float p0 = x0 * wA.x + x1 * wA.z, p1 = x0 * wA.y + x1 * wA.w;
        float p2 = x0 * wB.x + x1 * wB.z, p3 = x0 * wB.y + x1 * wB.w;
        float p4 = x0 * wC.x + x1 * wC.z, p5 = x0 * wC.y + x1 * wC.w;
        float p6 = x0 * wD.x + x1 * wD.z, p7 = x0 * wD.y + x1 * wD.w;
#pragma unroll
        for (int m = 32; m >= 1; m >>= 1) {
            p0 += __shfl_xor(p0, m, 64); p1 += __shfl_xor(p1, m, 64);
            p2 += __shfl_xor(p2, m, 64); p3 += __shfl_xor(p3, m, 64);
            p4 += __shfl_xor(p4, m, 64); p5 += __shfl_xor(p5, m, 64);
            p6 += __shfl_xor(p6, m, 64); p7 += __shfl_xor(p7, m, 64);
        }
        if (lane == 0) {
            float4* o = (float4*)&aS[(size_t)n * 8];
            o[0] = make_float4(p0, p1, p2, p3);
            o[1] = make_float4(p4, p5, p6, p7);
        }
    }
}

// ---------------------------------------------------------------------------
// Two-level bucketed CSR build, LDS-aggregated atomics (unchanged from r6)
// ---------------------------------------------------------------------------
__device__ inline void edge_decode(int e, const int* js_src, const int* js_dst,
                                   const int* sj_src, const int* sj_dst,
                                   const int* ss_src, const int* ss_dst,
                                   int& src, int& bin) {
    if (e < E_JS) { src = js_src[e]; bin = js_dst[e]; }
    else if (e < E_JS + E_SJ) { int i = e - E_JS; src = sj_src[i]; bin = NS + sj_dst[i]; }
    else if (e < E_JS + E_SJ + E_SS) { int i = e - E_JS - E_SJ; src = ss_src[i]; bin = NS + NJ + ss_dst[i]; }
    else { int i = e - E_JS - E_SJ - E_SS; src = i; bin = NS + NJ + i; }
}

__global__ __launch_bounds__(1024) void k_bucket_hist(
    const int* __restrict__ js_src, const int* __restrict__ js_dst,
    const int* __restrict__ sj_src, const int* __restrict__ sj_dst,
    const int* __restrict__ ss_src, const int* __restrict__ ss_dst,
    int* __restrict__ bcnt) {
    __shared__ int lh[NBUK];
    for (int i = threadIdx.x; i < NBUK; i += 1024) lh[i] = 0;
    __syncthreads();
    for (int e = blockIdx.x * 1024 + threadIdx.x; e < ETOT; e += gridDim.x * 1024) {
        int src, bin;
        edge_decode(e, js_src, js_dst, sj_src, sj_dst, ss_src, ss_dst, src, bin);
        atomicAdd(&lh[bin >> 6], 1);
    }
    __syncthreads();
    for (int i = threadIdx.x; i < NBUK; i += 1024) {
        int v = lh[i];
        if (v) atomicAdd(&bcnt[i], v);
    }
}

__global__ void k_bucket_scan(const int* __restrict__ bcnt, int* __restrict__ bukoff,
                              int* __restrict__ bukcur) {
    __shared__ int sd[1024];
    int t = threadIdx.x;
    int v = (t < NBUK) ? bcnt[t] : 0;
    sd[t] = v;
    __syncthreads();
    for (int off = 1; off < 1024; off <<= 1) {
        int tmp = (t >= off) ? sd[t - off] : 0;
        __syncthreads();
        sd[t] += tmp;
        __syncthreads();
    }
    if (t < NBUK) { int ex = sd[t] - v; bukoff[t] = ex; bukcur[t] = ex; }
    if (t == 0) bukoff[NBUK] = ETOT;
}

__global__ __launch_bounds__(1024) void k_scatter_pairs(
    const int* __restrict__ js_src, const int* __restrict__ js_dst,
    const int* __restrict__ sj_src, const int* __restrict__ sj_dst,
    const int* __restrict__ ss_src, const int* __restrict__ ss_dst,
    int* __restrict__ bukcur, uint2* __restrict__ pairs) {
    __shared__ int lh[NBUK];
    __shared__ int lbase[NBUK];
    const int CH = (ETOT + (int)gridDim.x - 1) / (int)gridDim.x;
    const int beg = blockIdx.x * CH;
    const int endi = (beg + CH < ETOT) ? beg + CH : ETOT;
    for (int i = threadIdx.x; i < NBUK; i += 1024) lh[i] = 0;
    __syncthreads();
    for (int e = beg + threadIdx.x; e < endi; e += 1024) {
        int src, bin;
        edge_decode(e, js_src, js_dst, sj_src, sj_dst, ss_src, ss_dst, src, bin);
        atomicAdd(&lh[bin >> 6], 1);
    }
    __syncthreads();
    for (int i = threadIdx.x; i < NBUK; i += 1024) {
        int v = lh[i];
        lbase[i] = v ? atomicAdd(&bukcur[i], v) : 0;
    }
    __syncthreads();
    for (int i = threadIdx.x; i < NBUK; i += 1024) lh[i] = 0;
    __syncthreads();
    for (int e = beg + threadIdx.x; e < endi; e += 1024) {
        int src, bin;
        edge_decode(e, js_src, js_dst, sj_src, sj_dst, ss_src, ss_dst, src, bin);
        int bu = bin >> 6;
        int pos = lbase[bu] + atomicAdd(&lh[bu], 1);
        pairs[pos] = make_uint2((unsigned)src, (unsigned)bin);
    }
}

__global__ __launch_bounds__(256) void k_finalize(
    const uint2* __restrict__ pairs, const int* __restrict__ bukoff,
    int* __restrict__ offs, int* __restrict__ esrc) {
    int b = blockIdx.x, t = threadIdx.x;
    int base = bukoff[b], endi = bukoff[b + 1];
    __shared__ int cnt[64], excl[64], curs[64];
    if (t < 64) cnt[t] = 0;
    __syncthreads();
    for (int i = base + t; i < endi; i += 256)
        atomicAdd(&cnt[pairs[i].y & 63], 1);
    __syncthreads();
    if (t < 64) {
        int v = cnt[t];
        int inc = v;
#pragma unroll
        for (int off = 1; off < 64; off <<= 1) {
            int tmp = __shfl_up(inc, off, 64);
            if (t >= off) inc += tmp;
        }
        excl[t] = inc - v;
        curs[t] = inc - v;
    }
    __syncthreads();
    for (int i = base + t; i < endi; i += 256) {
        uint2 p = pairs[i];
        int lb = p.y & 63;
        int pos = atomicAdd(&curs[lb], 1);
        esrc[base + pos] = (int)p.x;
    }
    if (t < 64) {
        int bin = b * 64 + t;
        if (bin < NBINS) offs[bin] = base + excl[t];
    }
    if (b == 0 && t == 0) offs[NBINS] = ETOT;
}

// ---------------------------------------------------------------------------
// Combined gather for one layer: skill dsts do js+ss (one fused write of os),
// job dsts do sj (write oj). 4-way unrolled edge loop (clamped tail).
// ---------------------------------------------------------------------------
__device__ inline void edge_accum(
    const int* __restrict__ esrc, int beg, int endi,
    const float* __restrict__ aSrc, int sStride, int hOff, float ad,
    const unsigned short* __restrict__ hs, int hsLd, int c,
    float& ax, float& ay, float& az, float& aw, float& den) {
    for (int j = beg; j < endi; j += 4) {
        int j1 = j + 1 < endi ? j + 1 : endi - 1;
        int j2 = j + 2 < endi ? j + 2 : endi - 1;
        int j3 = j + 3 < endi ? j + 3 : endi - 1;
        int s0 = esrc[j], s1 = esrc[j1], s2 = esrc[j2], s3 = esrc[j3];
        float as0 = aSrc[(size_t)s0 * sStride + hOff];
        float as1 = aSrc[(size_t)s1 * sStride + hOff];
        float as2 = aSrc[(size_t)s2 * sStride + hOff];
        float as3 = aSrc[(size_t)s3 * sStride + hOff];
        ushort4 v0 = *(const ushort4*)&hs[(size_t)s0 * hsLd + c];
        ushort4 v1 = *(const ushort4*)&hs[(size_t)s1 * hsLd + c];
        ushort4 v2 = *(const ushort4*)&hs[(size_t)s2 * hsLd + c];
        ushort4 v3 = *(const ushort4*)&hs[(size_t)s3 * hsLd + c];
        float e0 = as0 + ad; e0 = e0 > 0.f ? e0 : 0.2f * e0;
        float e1 = as1 + ad; e1 = e1 > 0.f ? e1 : 0.2f * e1;
        float e2 = as2 + ad; e2 = e2 > 0.f ? e2 : 0.2f * e2;
        float e3 = as3 + ad; e3 = e3 > 0.f ? e3 : 0.2f * e3;
        float p0 = __expf(e0);
        float p1 = (j + 1 < endi) ? __expf(e1) : 0.f;
        float p2 = (j + 2 < endi) ? __expf(e2) : 0.f;
        float p3 = (j + 3 < endi) ? __expf(e3) : 0.f;
        ax += p0 * bf2f(v0.x) + p1 * bf2f(v1.x) + p2 * bf2f(v2.x) + p3 * bf2f(v3.x);
        ay += p0 * bf2f(v0.y) + p1 * bf2f(v1.y) + p2 * bf2f(v2.y) + p3 * bf2f(v3.y);
        az += p0 * bf2f(v0.z) + p1 * bf2f(v1.z) + p2 * bf2f(v2.z) + p3 * bf2f(v3.z);
        aw += p0 * bf2f(v0.w) + p1 * bf2f(v1.w) + p2 * bf2f(v2.w) + p3 * bf2f(v3.w);
        den += p0 + p1 + p2 + p3;
    }
}

__global__ __launch_bounds__(256) void k_gather_all(
    const int* __restrict__ offs, const int* __restrict__ esrc,
    const float* __restrict__ aJ, const float* __restrict__ aS,
    const unsigned short* __restrict__ hs1, const unsigned short* __restrict__ hs2,
    const float* __restrict__ gb,     // gat_b + l3*256
    unsigned short* __restrict__ oj, unsigned short* __restrict__ os) {
    int wave = threadIdx.x >> 6, lane = threadIdx.x & 63;
    int idx = blockIdx.x * 4 + wave;
    int c = lane * 4;
    int h = (c >= 128) ? 1 : 0;
    if (idx < NS) {
        int d = idx;
        // js relation (bins [0,NS)); src = jobs
        float axA = 0.f, ayA = 0.f, azA = 0.f, awA = 0.f, denA = 0.f;
        edge_accum(esrc, offs[d], offs[d + 1], aJ, 4, h, aS[(size_t)d * 8 + 2 + h],
                   hs1, 256, c, axA, ayA, azA, awA, denA);
        // ss relation (bins [NS+NJ,NBINS)); src = skills
        float axB = 0.f, ayB = 0.f, azB = 0.f, awB = 0.f, denB = 0.f;
        int bb = NS + NJ + d;
        edge_accum(esrc, offs[bb], offs[bb + 1], aS, 8, h, aS[(size_t)d * 8 + 6 + h],
                   hs2 + 256, 512, c, axB, ayB, azB, awB, denB);
        float scA = 1.f / (denA + 1e-16f);
        float scB = 1.f / (denB + 1e-16f);
        float4 bA = *(const float4*)&gb[c];          // bias js
        float4 bB = *(const float4*)&gb[512 + c];    // bias ss
        float o0 = axA * scA + bA.x + axB * scB + bB.x;
        float o1 = ayA * scA + bA.y + ayB * scB + bB.y;
        float o2 = azA * scA + bA.z + azB * scB + bB.z;
        float o3 = awA * scA + bA.w + awB * scB + bB.w;
        ushort4 o; o.x = f2bf(o0); o.y = f2bf(o1); o.z = f2bf(o2); o.w = f2bf(o3);
        *(ushort4*)&os[(size_t)d * 256 + c] = o;
    } else if (idx < NS + NJ) {
        int d = idx - NS;
        // sj relation (bins [NS,NS+NJ)); src = skills
        float ax = 0.f, ay = 0.f, az = 0.f, aw = 0.f, den = 0.f;
        int bb = NS + d;
        edge_accum(esrc, offs[bb], offs[bb + 1], aS, 8, 4 + h, aJ[(size_t)d * 4 + 2 + h],
                   hs2, 512, c, ax, ay, az, aw, den);
        float sc = 1.f / (den + 1e-16f);
        float4 b4 = *(const float4*)&gb[256 + c];    // bias sj
        float o0 = ax * sc + b4.x, o1 = ay * sc + b4.y;
        float o2 = az * sc + b4.z, o3 = aw * sc + b4.w;
        ushort4 o; o.x = f2bf(o0); o.y = f2bf(o1); o.z = f2bf(o2); o.w = f2bf(o3);
        *(ushort4*)&oj[(size_t)d * 256 + c] = o;
    }
}

// ---------------------------------------------------------------------------
extern "C" void kernel_launch(void* const* d_in, const int* in_sizes, int n_in,
                              void* d_out, int out_size, void* d_ws, size_t ws_size,
                              hipStream_t stream) {
    const float* x_job   = (const float*)d_in[0];
    const float* x_skill = (const float*)d_in[1];
    const int* js_src = (const int*)d_in[2];
    const int* js_dst = (const int*)d_in[3];
    const int* sj_src = (const int*)d_in[4];
    const int* sj_dst = (const int*)d_in[5];
    const int* ss_src = (const int*)d_in[6];
    const int* ss_dst = (const int*)d_in[7];
    const float* query    = (const float*)d_in[8];
    const float* W0_job   = (const float*)d_in[9];
    const float* b0_job   = (const float*)d_in[10];
    const float* g0_job   = (const float*)d_in[11];
    const float* be0_job  = (const float*)d_in[12];
    const float* W0_skill = (const float*)d_in[13];
    const float* b0_skill = (const float*)d_in[14];
    const float* g0_skill = (const float*)d_in[15];
    const float* be0_skill= (const float*)d_in[16];
    const float* gat_Ws = (const float*)d_in[17];
    const float* gat_Wd = (const float*)d_in[18];
    const float* gat_as = (const float*)d_in[19];
    const float* gat_ad = (const float*)d_in[20];
    const float* gat_b  = (const float*)d_in[21];
    const float* inter_W = (const float*)d_in[22];
    const float* inter_b = (const float*)d_in[23];
    const float* Wjf = (const float*)d_in[24];
    const float* bjf = (const float*)d_in[25];
    const float* Wq  = (const float*)d_in[26];
    const float* bq  = (const float*)d_in[27];

    // workspace carve (256B aligned bump allocator)
    char* w = (char*)d_ws;
    auto alloc = [&](size_t bytes) -> void* {
        void* p = (void*)w;
        w += (bytes + 255) & ~(size_t)255;
        return p;
    };
    u16* xj  = (u16*)alloc((size_t)NJ * 128 * 2);
    u16* xs  = (u16*)alloc((size_t)NS * 128 * 2);
    u16* hs1 = (u16*)alloc((size_t)NJ * 256 * 2);   // job-side projection (js)
    u16* hs2 = (u16*)alloc((size_t)NS * 512 * 2);   // skill-side: [sj | ss]
    u16* oj  = (u16*)alloc((size_t)NJ * 256 * 2);
    u16* os  = (u16*)alloc((size_t)NS * 256 * 2);
    u16* WtW0j = (u16*)alloc((size_t)SBERT * 128 * 2);
    u16* WtW0s = (u16*)alloc((size_t)SBERT * 128 * 2);
    u16* WtWs  = (u16*)alloc((size_t)6 * 128 * 256 * 2);   // [lr][256][128]
    u16* WtI   = (u16*)alloc((size_t)4 * 256 * 128 * 2);   // [i][128][256]
    u16* WtJf  = (u16*)alloc((size_t)128 * 128 * 2);
    float* aJ = (float*)alloc((size_t)NJ * 4 * 4);
    float* aS = (float*)alloc((size_t)NS * 8 * 4);
    float* wsa = (float*)alloc(6 * 256 * 4);
    float* wda = (float*)alloc(6 * 256 * 4);
    int* bcnt   = (int*)alloc((size_t)NBUK * 4);
    int* bukoff = (int*)alloc((size_t)(NBUK + 1) * 4);
    int* bukcur = (int*)alloc((size_t)NBUK * 4);
    uint2* pairs = (uint2*)alloc((size_t)ETOT * 8);
    int* offs = (int*)alloc((size_t)(NBINS + 1) * 4);
    int* esrc = (int*)alloc((size_t)ETOT * 4);

    float* out = (float*)d_out;
    float* scores  = out;
    float* job_emb = out + NJ;
    float* qv      = out + NJ + (size_t)NJ * 128;

    const int mbJ = cdiv(NJ, 64);   // 469
    const int mbS = cdiv(NS, 64);   // 188

    // --- prep: weight transposes + wa + bcnt zero + qvec (one dispatch) ---
    {
        PrepArgs A;
        A.m[0] = {W0_job, WtW0j, SBERT, 128};
        A.m[1] = {W0_skill, WtW0s, SBERT, 128};
        for (int lr = 0; lr < 6; ++lr)
            A.m[2 + lr] = {gat_Ws + (size_t)lr * 128 * 256, WtWs + (size_t)lr * 256 * 128, 128, 256};
        for (int i = 0; i < 4; ++i)
            A.m[8 + i] = {inter_W + (size_t)i * 256 * 128, WtI + (size_t)i * 128 * 256, 256, 128};
        A.m[12] = {Wjf, WtJf, 128, 128};
        A.Ws = gat_Ws; A.as_ = gat_as; A.Wd = gat_Wd; A.ad_ = gat_ad;
        A.wsa = wsa; A.wda = wda; A.bcnt = bcnt;
        A.query = query; A.Wq = Wq; A.bq = bq; A.qv = qv;
        k_prep<<<2509, 256, 0, stream>>>(A);
    }

    // --- bucketed CSR build, LDS-aggregated atomics ---
    k_bucket_hist<<<HIST_NB, 1024, 0, stream>>>(js_src, js_dst, sj_src, sj_dst,
                                                ss_src, ss_dst, bcnt);
    k_bucket_scan<<<1, 1024, 0, stream>>>(bcnt, bukoff, bukcur);
    k_scatter_pairs<<<SCAT_NB, 1024, 0, stream>>>(js_src, js_dst, sj_src, sj_dst,
                                                  ss_src, ss_dst, bukcur, pairs);
    k_finalize<<<NBUK, 256, 0, stream>>>(pairs, bukoff, offs, esrc);

    // --- initial linear + LN + relu (fp32 source, fused cast) ---
    {
        GPair P;
        P.a = {x_job, WtW0j, b0_job, g0_job, be0_job, xj, NJ, SBERT, 128, 128, 1, nullptr, nullptr};
        P.b = {x_skill, WtW0s, b0_skill, g0_skill, be0_skill, xs, NS, SBERT, 128, 128, 1, nullptr, nullptr};
        P.blocksA = mbJ;
        k_mgemm<3><<<dim3(mbJ + mbS, 1), 256, 0, stream>>>(P);
    }

    for (int l = 0; l < 2; ++l) {
        int l3 = l * 3;
        k_alpha_all<<<cdiv(NJ + NS, 4), 256, 0, stream>>>(xj, xs, wsa, wda, l3, aJ, aS);

        // projections: hs1 = xj @ Ws[js] (N=256); hs2 = xs @ [Ws[sj]|Ws[ss]] (N=512)
        {
            GPair P;
            P.a = {xj, WtWs + (size_t)(l3 + 0) * 256 * 128, nullptr, nullptr, nullptr,
                   hs1, NJ, 128, 256, 256, 0, nullptr, nullptr};
            P.b = {xs, WtWs + (size_t)(l3 + 1) * 256 * 128, nullptr, nullptr, nullptr,
                   hs2, NS, 128, 512, 512, 0, nullptr, nullptr};
            P.blocksA = mbJ;
            k_mgemm<0><<<dim3(mbJ + mbS, 4), 256, 0, stream>>>(P);
        }

        // combined gather (js+ss -> os, sj -> oj)
        k_gather_all<<<cdiv(NS + NJ, 4), 256, 0, stream>>>(
            offs, esrc, aJ, aS, hs1, hs2, gat_b + (size_t)l3 * 256, oj, os);

        // inter linears + relu (overwrite xj, xs)
        {
            GPair P;
            P.a = {oj, WtI + (size_t)(l * 2 + 0) * 128 * 256, inter_b + (size_t)(l * 2 + 0) * 128,
                   nullptr, nullptr, xj, NJ, 256, 128, 128, 0, nullptr, nullptr};
            P.b = {os, WtI + (size_t)(l * 2 + 1) * 128 * 256, inter_b + (size_t)(l * 2 + 1) * 128,
                   nullptr, nullptr, xs, NS, 256, 128, 128, 0, nullptr, nullptr};
            P.blocksA = mbJ;
            k_mgemm<2><<<dim3(mbJ + mbS, 1), 256, 0, stream>>>(P);
        }
    }

    // final projection (+ fused scores)
    {
        GPair P;
        P.a = {xj, WtJf, bjf, nullptr, nullptr, job_emb, NJ, 128, 128, 128, 0, qv, scores};
        P.b = P.a;
        P.blocksA = mbJ;
        k_mgemm<1><<<dim3(mbJ, 1), 256, 0, stream>>>(P);
    }
}